// Round 28
// baseline (33791.501 us; speedup 1.0000x reference)
//
#include <hip/hip_runtime.h>

// Farthest point sampling, B=32, N=32768, npoint=4096.
// R28 = R26 (8.06ms, proven L2->L1 ingest-bound: 256KB/step @ ~56B/cyc =
// 4680cyc of the 4830cyc step) + LDS xy-cache carve:
//  - LDS is 160KB/CU; z uses 128KB. The spare ~32KB caches the last 2044
//    float4 rows of xy (4088 points): chunk 14 fully from LDS, chunk 15
//    from LDS for tid<1020 (L2 for the 4-thread tail). Stream 256->224KB
//    per step (-12.4%).
//  - dynamic LDS (z at offset 0, xy cache at 131072); s_val/s_idx static.
//    State fits 60 VGPRs natively (R25) so the old dynamic-LDS VGPR
//    heuristic hazard is moot.
// Everything else = R26: value-only inner loop (fmax chain), DPP wave max
// (lane63) -> 32-bit LDS atomicMax -> B1 -> phase-B constant-index rescan
// (candidates only) -> atomicMin -> B2 -> 3-slot rotation reset; centroid
// xy from ws (L2 broadcast), z from LDS; ws xy pack kernel.
// First-occurrence argmax preserved (descending rescan ends at smallest i;
// min across candidates = numpy argmax). PASSING arithmetic (R6,
// bit-exact): d = fmaf(dz,dz, fmaf(dx,dx, dy*dy)), contract(off), fminf.
// Output float32: [B*NPOINT] idx, [B*NPOINT*3] coords.

#define BATCH  32
#define NPTS   32768
#define NPOINT 4096
#define NT     1024
#define NCH    16            // chunks of 2: 32 points per thread
#define XYROWS 2044          // cached float4 rows (4088 points)
#define ZBYTES (NPTS * 4)    // 131072
#define DYN_BYTES (ZBYTES + XYROWS * 16)       // 163776
#define WS_NEEDED ((size_t)BATCH * NPTS * 8)   // float2 xy per point = 8MB

#define DPP1(x, ctrl, rm) __builtin_amdgcn_update_dpp((x), (x), (ctrl), (rm), 0xf, false)

__device__ __forceinline__ float wave_max_dpp(float v) {
    unsigned int u = __float_as_uint(v);
    u = __float_as_uint(fmaxf(__uint_as_float(u), __uint_as_float(DPP1(u, 0xB1, 0xf))));
    u = __float_as_uint(fmaxf(__uint_as_float(u), __uint_as_float(DPP1(u, 0x4E, 0xf))));
    u = __float_as_uint(fmaxf(__uint_as_float(u), __uint_as_float(DPP1(u, 0x141, 0xf))));
    u = __float_as_uint(fmaxf(__uint_as_float(u), __uint_as_float(DPP1(u, 0x140, 0xf))));
    u = __float_as_uint(fmaxf(__uint_as_float(u), __uint_as_float(DPP1(u, 0x142, 0xa))));
    u = __float_as_uint(fmaxf(__uint_as_float(u), __uint_as_float(DPP1(u, 0x143, 0xc))));
    return __uint_as_float(u);   // lane 63 = wave max
}

// ---- prep: pack xy as float2[B][N] into ws (one-time, ~10us) ----
__global__ __launch_bounds__(256) void pack_xy(
    const float* __restrict__ xyz, float2* __restrict__ ws)
{
    const int i = blockIdx.x * 256 + threadIdx.x;   // 0 .. B*N-1
    ws[i] = make_float2(xyz[(size_t)i * 3 + 0], xyz[(size_t)i * 3 + 1]);
}

__global__ __launch_bounds__(NT, 1) void fps_kernel(
    const float* __restrict__ xyz,    // [B, N, 3] (setup only)
    const float2* __restrict__ wsxy,  // [B, N] packed xy
    float* __restrict__ out_idx,      // [B, NPOINT]
    float* __restrict__ out_xyz)      // [B, NPOINT, 3]
{
#pragma clang fp contract(off)
    extern __shared__ char smem[];
    float*  pz_lds  = (float*)smem;                    // [NPTS]
    float4* xy_lds  = (float4*)(smem + ZBYTES);        // [XYROWS]
    __shared__ unsigned int s_val[3];                  // dist bits
    __shared__ int s_idx[3];                           // winning index

    const int b   = blockIdx.x;
    const int tid = threadIdx.x;
    const float* base = xyz + (size_t)b * NPTS * 3;
    const float2* xy  = wsxy + (size_t)b * NPTS;
    const float4* xy4 = (const float4*)xy;             // 2 points per float4

    float dist[NCH * 2];
#pragma unroll
    for (int c = 0; c < NCH; ++c) {
        float xv[2], yv[2];
#pragma unroll
        for (int j = 0; j < 2; ++j) {
            const int g = c * 2048 + 2 * tid + j;
            xv[j] = base[g * 3 + 0];
            yv[j] = base[g * 3 + 1];
            pz_lds[g] = base[g * 3 + 2];
            dist[c * 2 + j] = 1e10f;
        }
        if (c >= 14) {                                 // fill xy cache
            const int row = (c - 14) * 1024 + tid;
            if (row < XYROWS)
                xy_lds[row] = make_float4(xv[0], yv[0], xv[1], yv[1]);
        }
    }
    if (tid == 0) {
        s_val[0] = 0u; s_val[1] = 0u; s_val[2] = 0u;
        s_idx[0] = 0x7fffffff; s_idx[1] = 0x7fffffff; s_idx[2] = 0x7fffffff;
    }
    __syncthreads();                       // LDS + slots ready

    int w = 1;   // RAN=False seed
    int p = 0;   // rotating slot index k%3

    for (int k = 0; k < NPOINT; ++k) {
        // Centroid: xy from ws (L2, same addr -> broadcast), z from LDS.
        const float2 cxy = xy[w];
        const float cz = pz_lds[w];
        const float cx = cxy.x, cy = cxy.y;
        if (tid == 0) {
            out_idx[(size_t)b * NPOINT + k] = (float)w;
            float* o = out_xyz + ((size_t)b * NPOINT + k) * 3;
            o[0] = cx; o[1] = cy; o[2] = cz;
        }

        // Distance update; VALUE-only tracking (fmax chain).
        float best = -1.0f;
#pragma unroll
        for (int c = 0; c < NCH; ++c) {
            float4 v;
            if (c < 14) {
                v = xy4[c * 1024 + tid];               // L2 stream
            } else if (c == 14) {
                v = xy_lds[tid];                       // LDS cache
            } else {                                   // c == 15
                if (tid < XYROWS - 1024) v = xy_lds[1024 + tid];
                else                     v = xy4[15 * 1024 + tid];
            }
            const float2 zz = *(const float2*)&pz_lds[c * 2048 + 2 * tid];
            {   // j = 0
                const float dx = v.x - cx;
                const float dy = v.y - cy;
                const float dz = zz.x - cz;
                const float d  = fmaf(dz, dz, fmaf(dx, dx, dy * dy));
                const float nd = fminf(dist[c * 2 + 0], d);
                dist[c * 2 + 0] = nd;
                best = fmaxf(best, nd);
            }
            {   // j = 1
                const float dx = v.z - cx;
                const float dy = v.w - cy;
                const float dz = zz.y - cz;
                const float d  = fmaf(dz, dz, fmaf(dx, dx, dy * dy));
                const float nd = fminf(dist[c * 2 + 1], d);
                dist[c * 2 + 1] = nd;
                best = fmaxf(best, nd);
            }
        }

        // Phase A: value-only wave max via DPP; lane 63 publishes.
        const float m = wave_max_dpp(best);
        if ((tid & 63) == 63)
            atomicMax(&s_val[p], __float_as_uint(m));
        __syncthreads();                   // B1: block max known
        const float M = __uint_as_float(s_val[p]);

        // Phase B (rare, exec-masked): candidates rescan dist[] for the
        // FIRST ==M (constant indices only) and publish the global index.
        if (best == M) {
            int li = 63;
#pragma unroll
            for (int i = 31; i >= 0; --i)
                if (dist[i] == M) li = i;          // ends at smallest i
            const int bi = (li >> 1) * 2048 + 2 * tid + (li & 1);
            atomicMin(&s_idx[p], bi);
        }
        __syncthreads();                   // B2: winning index known
        w = s_idx[p];
        // Reset slot for step k+2 (barriers of step k+1 order this write
        // before that slot's next atomics; its readers finished at k-1).
        const int pn2 = (p >= 1) ? (p - 1) : 2;   // (k+2)%3
        if (tid == 0) { s_val[pn2] = 0u; s_idx[pn2] = 0x7fffffff; }
        p = (p == 2) ? 0 : (p + 1);
    }
}

// ---------- fallback (R26 fallback, register xy): if ws too small ----------
__global__ __launch_bounds__(NT, 1)
__attribute__((amdgpu_num_vgpr(128)))
void fps_fallback(
    const float* __restrict__ xyz, float* __restrict__ out_idx,
    float* __restrict__ out_xyz)
{
#pragma clang fp contract(off)
    __shared__ float pz_lds[NPTS];
    __shared__ unsigned int s_val[3];
    __shared__ int s_idx[3];
    const int b = blockIdx.x, tid = threadIdx.x;
    const float* base = xyz + (size_t)b * NPTS * 3;
    float px[NCH * 2], py[NCH * 2], dist[NCH * 2];
#pragma unroll
    for (int c = 0; c < NCH; ++c)
#pragma unroll
        for (int j = 0; j < 2; ++j) {
            const int i = c * 2 + j, g = c * 2048 + 2 * tid + j;
            px[i] = base[g * 3 + 0]; py[i] = base[g * 3 + 1];
            pz_lds[g] = base[g * 3 + 2]; dist[i] = 1e10f;
        }
    if (tid == 0) {
        s_val[0] = 0u; s_val[1] = 0u; s_val[2] = 0u;
        s_idx[0] = 0x7fffffff; s_idx[1] = 0x7fffffff; s_idx[2] = 0x7fffffff;
    }
    __syncthreads();
    int w = 1, p = 0;
    for (int k = 0; k < NPOINT; ++k) {
        const float cx = base[w * 3 + 0], cy = base[w * 3 + 1],
                    cz = base[w * 3 + 2];
        if (tid == 0) {
            out_idx[(size_t)b * NPOINT + k] = (float)w;
            float* o = out_xyz + ((size_t)b * NPOINT + k) * 3;
            o[0] = cx; o[1] = cy; o[2] = cz;
        }
        float best = -1.0f; int lc = 63;
#pragma unroll
        for (int c = 0; c < NCH; ++c) {
            const float2 zz = *(const float2*)&pz_lds[c * 2048 + 2 * tid];
            const float pzv[2] = { zz.x, zz.y };
#pragma unroll
            for (int j = 0; j < 2; ++j) {
                const int i = c * 2 + j;
                const float dx = px[i] - cx, dy = py[i] - cy,
                            dz = pzv[j] - cz;
                const float d  = fmaf(dz, dz, fmaf(dx, dx, dy * dy));
                const float nd = fminf(dist[i], d);
                dist[i] = nd;
                if (nd > best) { best = nd; lc = 2 * c + j; }
            }
        }
        const float m = wave_max_dpp(best);
        if ((tid & 63) == 63) atomicMax(&s_val[p], __float_as_uint(m));
        __syncthreads();
        const float M = __uint_as_float(s_val[p]);
        if (best == M) {
            const int bi = (lc >> 1) * 2048 + 2 * tid + (lc & 1);
            atomicMin(&s_idx[p], bi);
        }
        __syncthreads();
        w = s_idx[p];
        const int pn2 = (p >= 1) ? (p - 1) : 2;
        if (tid == 0) { s_val[pn2] = 0u; s_idx[pn2] = 0x7fffffff; }
        p = (p == 2) ? 0 : (p + 1);
    }
}

extern "C" void kernel_launch(void* const* d_in, const int* in_sizes, int n_in,
                              void* d_out, int out_size, void* d_ws, size_t ws_size,
                              hipStream_t stream) {
    const float* xyz = (const float*)d_in[0];
    float* out = (float*)d_out;
    float* out_idx = out;                              // B*NPOINT floats
    float* out_xyz = out + (size_t)BATCH * NPOINT;     // B*NPOINT*3 floats

    if (ws_size >= WS_NEEDED) {
        float2* wsxy = (float2*)d_ws;
        pack_xy<<<(BATCH * NPTS) / 256, 256, 0, stream>>>(xyz, wsxy);
        (void)hipFuncSetAttribute((const void*)fps_kernel,
                                  hipFuncAttributeMaxDynamicSharedMemorySize,
                                  DYN_BYTES);
        fps_kernel<<<BATCH, NT, DYN_BYTES, stream>>>(xyz, wsxy,
                                                     out_idx, out_xyz);
    } else {
        fps_fallback<<<BATCH, NT, 0, stream>>>(xyz, out_idx, out_xyz);
    }
}

// Round 29
// 8352.273 us; speedup vs baseline: 4.0458x; 4.0458x over previous
//
#include <hip/hip_runtime.h>

// Farthest point sampling, B=32, N=32768, npoint=4096.
// R29 = R26 (8.06ms, proven) + xy LDS-cache done on the PROVEN STATIC-LDS
// codegen path. R28's 4x regression came from switching pz to dynamic LDS
// (SGPR 112->32 = different codegen regime, VALU stalled) plus a 164,288B
// > 163,840B LDS overrun -- not from the cache idea itself.
//  - ALL-STATIC LDS: pz[32768] (128KB) + xy_c[2016] float4 rows (31.5KB)
//    + slots = 163,352B <= 163,840B cap.
//  - chunk 14: xy fully from LDS; chunk 15: LDS for tid<992 (divergence
//    confined to half of wave 15), L2 for the 32-thread tail.
//    Stream 256 -> 224KB/step (-12.4% of the 4680cyc ingest term).
// Everything else byte-identical to R26: value-only inner loop, DPP wave
// max (lane63) -> 32-bit LDS atomicMax -> B1 -> phase-B constant-index
// rescan -> atomicMin -> B2 -> 3-slot rotation reset; centroid xy from ws
// (L2 broadcast), z from LDS; ws xy pack kernel.
// First-occurrence argmax preserved. PASSING arithmetic (R6, bit-exact):
// d = fmaf(dz,dz, fmaf(dx,dx, dy*dy)), contract(off), fminf chain.
// Output float32: [B*NPOINT] idx, [B*NPOINT*3] coords.

#define BATCH  32
#define NPTS   32768
#define NPOINT 4096
#define NT     1024
#define NCH    16            // chunks of 2: 32 points per thread
#define XYROWS 2016          // cached float4 rows (4032 points), 31.5KB
#define WS_NEEDED ((size_t)BATCH * NPTS * 8)   // float2 xy per point = 8MB

#define DPP1(x, ctrl, rm) __builtin_amdgcn_update_dpp((x), (x), (ctrl), (rm), 0xf, false)

__device__ __forceinline__ float wave_max_dpp(float v) {
    unsigned int u = __float_as_uint(v);
    u = __float_as_uint(fmaxf(__uint_as_float(u), __uint_as_float(DPP1(u, 0xB1, 0xf))));
    u = __float_as_uint(fmaxf(__uint_as_float(u), __uint_as_float(DPP1(u, 0x4E, 0xf))));
    u = __float_as_uint(fmaxf(__uint_as_float(u), __uint_as_float(DPP1(u, 0x141, 0xf))));
    u = __float_as_uint(fmaxf(__uint_as_float(u), __uint_as_float(DPP1(u, 0x140, 0xf))));
    u = __float_as_uint(fmaxf(__uint_as_float(u), __uint_as_float(DPP1(u, 0x142, 0xa))));
    u = __float_as_uint(fmaxf(__uint_as_float(u), __uint_as_float(DPP1(u, 0x143, 0xc))));
    return __uint_as_float(u);   // lane 63 = wave max
}

// ---- prep: pack xy as float2[B][N] into ws (one-time, ~10us) ----
__global__ __launch_bounds__(256) void pack_xy(
    const float* __restrict__ xyz, float2* __restrict__ ws)
{
    const int i = blockIdx.x * 256 + threadIdx.x;   // 0 .. B*N-1
    ws[i] = make_float2(xyz[(size_t)i * 3 + 0], xyz[(size_t)i * 3 + 1]);
}

__global__ __launch_bounds__(NT, 1) void fps_kernel(
    const float* __restrict__ xyz,    // [B, N, 3] (setup only)
    const float2* __restrict__ wsxy,  // [B, N] packed xy
    float* __restrict__ out_idx,      // [B, NPOINT]
    float* __restrict__ out_xyz)      // [B, NPOINT, 3]
{
#pragma clang fp contract(off)
    __shared__ float  pz_lds[NPTS];              // 128 KB static
    __shared__ float4 xy_lds[XYROWS];            // 31.5 KB static
    __shared__ unsigned int s_val[3];            // dist bits (>=0, monotone)
    __shared__ int s_idx[3];                     // winning global index

    const int b   = blockIdx.x;
    const int tid = threadIdx.x;
    const float* base = xyz + (size_t)b * NPTS * 3;
    const float2* xy  = wsxy + (size_t)b * NPTS;
    const float4* xy4 = (const float4*)xy;       // 2 points per float4

    float dist[NCH * 2];
#pragma unroll
    for (int c = 0; c < NCH; ++c) {
        float xv[2], yv[2];
#pragma unroll
        for (int j = 0; j < 2; ++j) {
            const int g = c * 2048 + 2 * tid + j;
            xv[j] = base[g * 3 + 0];
            yv[j] = base[g * 3 + 1];
            pz_lds[g] = base[g * 3 + 2];
            dist[c * 2 + j] = 1e10f;
        }
        if (c >= 14) {                           // fill xy cache
            const int row = (c - 14) * 1024 + tid;
            if (row < XYROWS)
                xy_lds[row] = make_float4(xv[0], yv[0], xv[1], yv[1]);
        }
    }
    if (tid == 0) {
        s_val[0] = 0u; s_val[1] = 0u; s_val[2] = 0u;
        s_idx[0] = 0x7fffffff; s_idx[1] = 0x7fffffff; s_idx[2] = 0x7fffffff;
    }
    __syncthreads();                       // LDS + slots ready

    int w = 1;   // RAN=False seed
    int p = 0;   // rotating slot index k%3

    for (int k = 0; k < NPOINT; ++k) {
        // Centroid: xy from ws (L2, same addr -> broadcast), z from LDS.
        const float2 cxy = xy[w];
        const float cz = pz_lds[w];
        const float cx = cxy.x, cy = cxy.y;
        if (tid == 0) {
            out_idx[(size_t)b * NPOINT + k] = (float)w;
            float* o = out_xyz + ((size_t)b * NPOINT + k) * 3;
            o[0] = cx; o[1] = cy; o[2] = cz;
        }

        // Distance update; VALUE-only tracking (fmax chain).
        float best = -1.0f;
#pragma unroll
        for (int c = 0; c < NCH; ++c) {
            float4 v;
            if (c < 14) {
                v = xy4[c * 1024 + tid];               // L2 stream
            } else if (c == 14) {
                v = xy_lds[tid];                       // LDS cache
            } else {                                   // c == 15
                if (tid < XYROWS - 1024) v = xy_lds[1024 + tid];
                else                     v = xy4[15 * 1024 + tid];
            }
            const float2 zz = *(const float2*)&pz_lds[c * 2048 + 2 * tid];
            {   // j = 0
                const float dx = v.x - cx;
                const float dy = v.y - cy;
                const float dz = zz.x - cz;
                const float d  = fmaf(dz, dz, fmaf(dx, dx, dy * dy));
                const float nd = fminf(dist[c * 2 + 0], d);
                dist[c * 2 + 0] = nd;
                best = fmaxf(best, nd);
            }
            {   // j = 1
                const float dx = v.z - cx;
                const float dy = v.w - cy;
                const float dz = zz.y - cz;
                const float d  = fmaf(dz, dz, fmaf(dx, dx, dy * dy));
                const float nd = fminf(dist[c * 2 + 1], d);
                dist[c * 2 + 1] = nd;
                best = fmaxf(best, nd);
            }
        }

        // Phase A: value-only wave max via DPP; lane 63 publishes.
        const float m = wave_max_dpp(best);
        if ((tid & 63) == 63)
            atomicMax(&s_val[p], __float_as_uint(m));
        __syncthreads();                   // B1: block max known
        const float M = __uint_as_float(s_val[p]);

        // Phase B (rare, exec-masked): candidates rescan dist[] for the
        // FIRST ==M (constant indices only) and publish the global index.
        if (best == M) {
            int li = 63;
#pragma unroll
            for (int i = 31; i >= 0; --i)
                if (dist[i] == M) li = i;          // ends at smallest i
            const int bi = (li >> 1) * 2048 + 2 * tid + (li & 1);
            atomicMin(&s_idx[p], bi);
        }
        __syncthreads();                   // B2: winning index known
        w = s_idx[p];
        // Reset slot for step k+2 (barriers of step k+1 order this write
        // before that slot's next atomics; its readers finished at k-1).
        const int pn2 = (p >= 1) ? (p - 1) : 2;   // (k+2)%3
        if (tid == 0) { s_val[pn2] = 0u; s_idx[pn2] = 0x7fffffff; }
        p = (p == 2) ? 0 : (p + 1);
    }
}

// ---------- fallback (R26 fallback, register xy): if ws too small ----------
__global__ __launch_bounds__(NT, 1)
__attribute__((amdgpu_num_vgpr(128)))
void fps_fallback(
    const float* __restrict__ xyz, float* __restrict__ out_idx,
    float* __restrict__ out_xyz)
{
#pragma clang fp contract(off)
    __shared__ float pz_lds[NPTS];
    __shared__ unsigned int s_val[3];
    __shared__ int s_idx[3];
    const int b = blockIdx.x, tid = threadIdx.x;
    const float* base = xyz + (size_t)b * NPTS * 3;
    float px[NCH * 2], py[NCH * 2], dist[NCH * 2];
#pragma unroll
    for (int c = 0; c < NCH; ++c)
#pragma unroll
        for (int j = 0; j < 2; ++j) {
            const int i = c * 2 + j, g = c * 2048 + 2 * tid + j;
            px[i] = base[g * 3 + 0]; py[i] = base[g * 3 + 1];
            pz_lds[g] = base[g * 3 + 2]; dist[i] = 1e10f;
        }
    if (tid == 0) {
        s_val[0] = 0u; s_val[1] = 0u; s_val[2] = 0u;
        s_idx[0] = 0x7fffffff; s_idx[1] = 0x7fffffff; s_idx[2] = 0x7fffffff;
    }
    __syncthreads();
    int w = 1, p = 0;
    for (int k = 0; k < NPOINT; ++k) {
        const float cx = base[w * 3 + 0], cy = base[w * 3 + 1],
                    cz = base[w * 3 + 2];
        if (tid == 0) {
            out_idx[(size_t)b * NPOINT + k] = (float)w;
            float* o = out_xyz + ((size_t)b * NPOINT + k) * 3;
            o[0] = cx; o[1] = cy; o[2] = cz;
        }
        float best = -1.0f; int lc = 63;
#pragma unroll
        for (int c = 0; c < NCH; ++c) {
            const float2 zz = *(const float2*)&pz_lds[c * 2048 + 2 * tid];
            const float pzv[2] = { zz.x, zz.y };
#pragma unroll
            for (int j = 0; j < 2; ++j) {
                const int i = c * 2 + j;
                const float dx = px[i] - cx, dy = py[i] - cy,
                            dz = pzv[j] - cz;
                const float d  = fmaf(dz, dz, fmaf(dx, dx, dy * dy));
                const float nd = fminf(dist[i], d);
                dist[i] = nd;
                if (nd > best) { best = nd; lc = 2 * c + j; }
            }
        }
        const float m = wave_max_dpp(best);
        if ((tid & 63) == 63) atomicMax(&s_val[p], __float_as_uint(m));
        __syncthreads();
        const float M = __uint_as_float(s_val[p]);
        if (best == M) {
            const int bi = (lc >> 1) * 2048 + 2 * tid + (lc & 1);
            atomicMin(&s_idx[p], bi);
        }
        __syncthreads();
        w = s_idx[p];
        const int pn2 = (p >= 1) ? (p - 1) : 2;
        if (tid == 0) { s_val[pn2] = 0u; s_idx[pn2] = 0x7fffffff; }
        p = (p == 2) ? 0 : (p + 1);
    }
}

extern "C" void kernel_launch(void* const* d_in, const int* in_sizes, int n_in,
                              void* d_out, int out_size, void* d_ws, size_t ws_size,
                              hipStream_t stream) {
    const float* xyz = (const float*)d_in[0];
    float* out = (float*)d_out;
    float* out_idx = out;                              // B*NPOINT floats
    float* out_xyz = out + (size_t)BATCH * NPOINT;     // B*NPOINT*3 floats

    if (ws_size >= WS_NEEDED) {
        float2* wsxy = (float2*)d_ws;
        pack_xy<<<(BATCH * NPTS) / 256, 256, 0, stream>>>(xyz, wsxy);
        fps_kernel<<<BATCH, NT, 0, stream>>>(xyz, wsxy, out_idx, out_xyz);
    } else {
        fps_fallback<<<BATCH, NT, 0, stream>>>(xyz, out_idx, out_xyz);
    }
}